// Round 1
// baseline (153.863 us; speedup 1.0000x reference)
//
#include <hip/hip_runtime.h>
#include <math.h>

#define NQ 12
#define NL 4
#define NA 6
#define BATCH 4096
#define NT 256

typedef float f2 __attribute__((ext_vector_type(2)));

// HW-verified (R3-R10) packed complex primitives; (re,im) in a VGPR pair.
#define CMUL(d, u, a)  asm("v_pk_mul_f32 %0, %1, %2 op_sel_hi:[0,1]"                 : "=v"(d) : "v"(u), "v"(a))
#define CMACR(d, u, a) asm("v_pk_fma_f32 %0, %1, %2, %0 op_sel_hi:[0,1,1]"           : "+v"(d) : "v"(u), "v"(a))
#define CMACI(d, u, a) asm("v_pk_fma_f32 %0, %1, %2, %0 op_sel:[1,1,0] op_sel_hi:[1,0,1] neg_lo:[1,0,0]" : "+v"(d) : "v"(u), "v"(a))
// R10-verified scalar-broadcast variants (coefficient f2 = (c,s)):
#define RYMULS(d, u, a)  asm("v_pk_mul_f32 %0, %1, %2 op_sel:[1,0] op_sel_hi:[1,1]"  : "=v"(d) : "v"(u), "v"(a))
#define RYMACNS(d, u, a) asm("v_pk_fma_f32 %0, %1, %2, %0 op_sel:[1,0,0] op_sel_hi:[1,1,1] neg_lo:[1,0,0] neg_hi:[1,0,0]" : "+v"(d) : "v"(u), "v"(a))
#define WFENCE() asm volatile("s_waitcnt lgkmcnt(0)" ::: "memory")

// Real RY butterfly: n0 = c*a0 - s*a1 ; n1 = s*a0 + c*a1   (4 pk ops)
#define RYBFLY(A0, A1, CS) do { \
    f2 _a0 = (A0), _a1 = (A1), _n0, _n1; \
    CMUL  (_n0, CS, _a0); RYMACNS(_n0, CS, _a1); \
    RYMULS(_n1, CS, _a0); CMACR  (_n1, CS, _a1); \
    (A0) = _n0; (A1) = _n1; } while (0)

#define RYGATE(gidx, bq) do { \
    const f2 cs = *(const f2*)(rots + (gidx) * 2); \
    const int S = 1 << (bq); \
    _Pragma("unroll") \
    for (int m = 0; m < 8; ++m) { \
        const int j0 = ((m & ~(S - 1)) << 1) | (m & (S - 1)); \
        RYBFLY(st[j0], st[j0 + S], cs); \
    } } while (0)

// Circuit algebra (R10-verified): Rot = RZ(omega)*RY(theta)*RZ(phi); diagonals folded:
// RZ(phi_0) into init; D_l = RZ(omega_l)*CZ*RZ(phi_{l+1}) between RY layers; trailing
// RZ(omega_3)+CZ_3 dropped (probs phase-invariant).
// Layouts (R8-verified): L1: i=(lam5..lam0,w1,w0,j3..j0); L2: i=(lam5,lam4,j3..j0,w1,w0,lam3..0);
// L3: i=(j3,j2,lam5,lam4,w1,w0,j1,j0,lam3..0).
// T_a (L1<->L2, involution, wave-local) / T_b (L2<->L3, involution, cross-wave): R8 formulas.
// R11: buf shrunk 17-stride pad -> stride-16 XOR swizzle (phys col = (c ^ r) & 15).
//   Bank floor preserved (writes/T_a/T_b all 4-dword/bank, verified by construction above).
//   encc/encs (init-only) and red/qout (epilogue-only) overlaid inside buf; one extra
//   __syncthreads() on each side closes the cross-wave liveness windows.
//   LDS = 32768 B exactly -> 5 blocks/CU (was 4 at 35328 B).
// d_ws float layout: [0..95] 48 gates (c,s) | [96..143] alphas[4][12] | [144..271] dreg[4][16] (re,im)

__global__ void setup_kernel(const float* __restrict__ weights, float* __restrict__ ws) {
    const int t = threadIdx.x;   // 64 threads
    if (t < NL * NQ) {
        const float th = weights[t * 3 + 1];
        float s, c;
        sincosf(0.5f * th, &s, &c);
        ws[t * 2 + 0] = c; ws[t * 2 + 1] = s;
        const int r = t / NQ, q = t % NQ;
        float a;
        if (r == 0) a = 0.5f * weights[q * 3 + 0];
        else        a = 0.5f * (weights[((r - 1) * NQ + q) * 3 + 2] +
                                 weights[(r * NQ + q) * 3 + 0]);
        ws[96 + t] = a;
    }
    {
        const int d = t >> 4, j = t & 15;
        int wq[4];
        if (d == 1 || d == 3) { wq[0] = 0; wq[1] = 1; wq[2] = 6; wq[3] = 7; }
        else                  { wq[0] = 8; wq[1] = 9; wq[2] = 10; wq[3] = 11; }
        float g = 0.0f;
#pragma unroll
        for (int k = 0; k < 4; ++k) {
            const int q = wq[k];
            const float a = (d == 0) ? 0.5f * weights[q * 3 + 0]
                                     : 0.5f * (weights[((d - 1) * NQ + q) * 3 + 2] +
                                               weights[(d * NQ + q) * 3 + 0]);
            g += ((j >> (3 - k)) & 1) ? a : -a;
        }
        float sg, cg;
        sincosf(g, &sg, &cg);
        ws[144 + (d * 16 + j) * 2 + 0] = cg;
        ws[144 + (d * 16 + j) * 2 + 1] = sg;
    }
}

// st[j] *= (cos b, sin b) * dreg_tab[j]   (R10-verified)
__device__ __forceinline__ void apply_phase(f2* st, const float* tab, float beta) {
    float sb, cb;
    sincosf(beta, &sb, &cb);
    const f2 Dth = (f2){cb, sb};
#pragma unroll
    for (int j = 0; j < 16; ++j) {
        const f2 a = st[j];
        f2 t, u;
        CMUL(t, Dth, a); CMACI(t, Dth, a);
        const f2 dg = *(const f2*)(tab + 2 * j);
        CMUL(u, dg, t); CMACI(u, dg, t);
        st[j] = u;
    }
}

__global__ __launch_bounds__(NT) void qdqn_kernel(
    const float* __restrict__ x,       // [BATCH,12]
    const float* __restrict__ rots,    // d_ws tables
    const float* __restrict__ fc_w,    // [6,12]
    const float* __restrict__ fc_b,    // [6]
    float* __restrict__ out)           // [BATCH,6]
{
    // 32768 B total LDS: stride-16 XOR-swizzled transpose buffer; small arrays overlaid.
    __shared__ __align__(16) f2 buf[NT * 16];
    float* const encc  = (float*)buf;        // [12]      live: init only (pre-loop barrier)
    float* const encs  = (float*)buf + 12;   // [12]
    float* const redp  = (float*)buf + 24;   // [4][12]   live: epilogue only (post barrier)
    float* const qoutp = (float*)buf + 72;   // [12]

    const int tix = threadIdx.x;
    const int lam = tix & 63;
    const int w   = tix >> 6;
    const int w1  = (w >> 1) & 1, w0 = w & 1;
    const int b   = blockIdx.x;

    const float* alph = rots + 96;
    const float* dreg = rots + 144;

    if (tix < NQ) {
        float s, c;
        sincosf(0.5f * x[b * NQ + tix], &s, &c);
        encc[tix] = c; encs[tix] = s;
    }
    __syncthreads();

    // --- RY product state in L1 (real) ---
    f2 st[16];
    {
        float pre = 1.0f;
#pragma unroll
        for (int q = 0; q < 6; ++q)
            pre *= ((lam >> (5 - q)) & 1) ? encs[q] : encc[q];
        pre *= w1 ? encs[6] : encc[6];
        pre *= w0 ? encs[7] : encc[7];
        const float c8 = encc[8],  s8 = encs[8];
        const float c9 = encc[9],  s9 = encs[9];
        const float cA = encc[10], sA = encs[10];
        const float cB = encc[11], sB = encs[11];
#pragma unroll
        for (int j = 0; j < 16; ++j) {
            float v = pre;
            v *= (j & 8) ? s8 : c8;
            v *= (j & 4) ? s9 : c9;
            v *= (j & 2) ? sA : cA;
            v *= (j & 1) ? sB : cB;
            st[j] = (f2){ v, 0.0f };
        }
    }

#define BETA_L1(al) ( (((lam >> 5) & 1) ? (al)[0] : -(al)[0]) + (((lam >> 4) & 1) ? (al)[1] : -(al)[1]) \
                    + (((lam >> 3) & 1) ? (al)[2] : -(al)[2]) + (((lam >> 2) & 1) ? (al)[3] : -(al)[3]) \
                    + (((lam >> 1) & 1) ? (al)[4] : -(al)[4]) + (((lam >> 0) & 1) ? (al)[5] : -(al)[5]) \
                    + (w1 ? (al)[6] : -(al)[6]) + (w0 ? (al)[7] : -(al)[7]) )
#define BETA_L3(al) ( (((lam >> 5) & 1) ? (al)[2] : -(al)[2]) + (((lam >> 4) & 1) ? (al)[3] : -(al)[3]) \
                    + (w1 ? (al)[4] : -(al)[4]) + (w0 ? (al)[5] : -(al)[5]) \
                    + (((lam >> 3) & 1) ? (al)[8] : -(al)[8]) + (((lam >> 2) & 1) ? (al)[9] : -(al)[9]) \
                    + (((lam >> 1) & 1) ? (al)[10] : -(al)[10]) + (((lam >> 0) & 1) ? (al)[11] : -(al)[11]) )

    // --- init diagonal: RZ(phi_0) in L1 ---
    apply_phase(st, dreg + 0 * 32, BETA_L1(alph + 0 * NQ));

    const int col_b = ((lam >> 4) << 2) | w;
    const int row_a = (w << 6) | (lam & 0x30);
    const int col_a = lam & 0xF;

    // Swizzled buf addressing (f2 index). Logical (row r, col c) -> phys r*16 + ((c^r)&15).
    const int bw      = (tix << 4)   | (tix & 15);           // write:   buf[bw ^ j]  (r=tix, c=j)
    const int ta_base = (row_a << 4) | col_a;                // T_a rd:  buf[ta_base ^ (j*17)]
    const int tb_base = ((lam & 15) << 4) | (col_b ^ (lam & 15)); // T_b rd: base | j-immediates

#define TRANSPOSE_A_FWD() do { \
    WFENCE(); \
    _Pragma("unroll") for (int j = 0; j < 16; ++j) buf[bw ^ j] = st[j]; \
    WFENCE(); \
    _Pragma("unroll") for (int j = 0; j < 16; ++j) st[j] = buf[ta_base ^ (j * 17)]; \
    } while (0)

#define TB_READ(j) buf[tb_base | ((j & 3) << 10) | ((j >> 2) << 8)]

    // close encc/encs liveness (overlaid in buf) before first buf write
    __syncthreads();

#pragma unroll 1
    for (int h = 0; h < 2; ++h) {
        // ============ forward layer l = 2h : L1 -> L2 -> L3 ============
        {
            const int gb = (2 * h) * NQ;
            RYGATE(gb + 11, 0); RYGATE(gb + 10, 1); RYGATE(gb + 9, 2); RYGATE(gb + 8, 3);
            TRANSPOSE_A_FWD();                      // wave-local (prior readers in-wave or none)
            RYGATE(gb + 5, 0); RYGATE(gb + 4, 1); RYGATE(gb + 3, 2); RYGATE(gb + 2, 3);
            // T_b (cross-wave reads)
            WFENCE();
#pragma unroll
            for (int j = 0; j < 16; ++j) buf[bw ^ j] = st[j];
            __syncthreads();
#pragma unroll
            for (int j = 0; j < 16; ++j) st[j] = TB_READ(j);
            RYGATE(gb + 7, 0); RYGATE(gb + 6, 1); RYGATE(gb + 1, 2); RYGATE(gb + 0, 3);
            // CZ sign in L3 (R8-verified)
            {
                const int l5 = (lam >> 5) & 1, l4 = (lam >> 4) & 1, l3 = (lam >> 3) & 1;
                const int par = (l5 & l4) + (l4 & w1) + (w1 & w0) + __popc(lam & (lam >> 1) & 0x7);
                const float base = (par & 1) ? -1.0f : 1.0f;
                const float fA = l5 ? -1.0f : 1.0f;
                const float fB = w0 ? -1.0f : 1.0f;
                const float fC = l3 ? -1.0f : 1.0f;
#pragma unroll
                for (int j = 0; j < 16; ++j) {
                    float s = base;
                    if (j & 4) s *= fA;
                    if (j & 2) s *= fB;
                    if (j & 1) s *= fC;
                    if ((((j & 12) == 12) ? 1 : 0) ^ (((j & 3) == 3) ? 1 : 0)) s = -s;
                    st[j] *= s;
                }
            }
            // fused RZ diagonal, row 2h+1, in L3
            apply_phase(st, dreg + (2 * h + 1) * 32, BETA_L3(alph + (2 * h + 1) * NQ));
        }
        // ============ reverse layer l = 2h+1 : L3 -> L2 -> L1 ============
        {
            const int gb = (2 * h + 1) * NQ;
            RYGATE(gb + 7, 0); RYGATE(gb + 6, 1); RYGATE(gb + 1, 2); RYGATE(gb + 0, 3);
            // T_b back (involution; prior T_b reads cross-wave -> barrier before writes)
            __syncthreads();
#pragma unroll
            for (int j = 0; j < 16; ++j) buf[bw ^ j] = st[j];
            __syncthreads();
#pragma unroll
            for (int j = 0; j < 16; ++j) st[j] = TB_READ(j);
            RYGATE(gb + 5, 0); RYGATE(gb + 4, 1); RYGATE(gb + 3, 2); RYGATE(gb + 2, 3);
            // T_a back (prior T_b reads cross-wave -> barrier before writes; reads wave-local)
            __syncthreads();
#pragma unroll
            for (int j = 0; j < 16; ++j) buf[bw ^ j] = st[j];
            WFENCE();
#pragma unroll
            for (int j = 0; j < 16; ++j) st[j] = buf[ta_base ^ (j * 17)];
            RYGATE(gb + 11, 0); RYGATE(gb + 10, 1); RYGATE(gb + 9, 2); RYGATE(gb + 8, 3);
            if (h == 0) {
                // CZ sign in L1 (R6/R8-verified)
                {
                    const int par = __popc(lam & (lam >> 1)) + ((lam & 1) & w1) + (w1 & w0);
                    const float base = (par & 1) ? -1.0f : 1.0f;
                    const float sHi = w0 ? -base : base;
#pragma unroll
                    for (int j = 0; j < 16; ++j) {
                        float s = (j & 8) ? sHi : base;
                        if (__popc(j & (j >> 1)) & 1) s = -s;
                        st[j] *= s;
                    }
                }
                // fused RZ diagonal, row 2, in L1
                apply_phase(st, dreg + 2 * 32, BETA_L1(alph + 2 * NQ));
            }
            // h==1: trailing diagonals dropped (probs phase-invariant)
        }
    }

    // --- measurement in L1 ---
    float tot = 0.f, m8 = 0.f, m9 = 0.f, m10 = 0.f, m11 = 0.f;
#pragma unroll
    for (int j = 0; j < 16; ++j) {
        const float p = st[j].x * st[j].x + st[j].y * st[j].y;
        tot += p;
        m8  += (j & 8) ? -p : p;
        m9  += (j & 4) ? -p : p;
        m10 += (j & 2) ? -p : p;
        m11 += (j & 1) ? -p : p;
    }
    float part[NQ];
#pragma unroll
    for (int q = 0; q < 6; ++q)
        part[q] = ((lam >> (5 - q)) & 1) ? -tot : tot;
    part[6] = w1 ? -tot : tot;
    part[7] = w0 ? -tot : tot;
    part[8] = m8; part[9] = m9; part[10] = m10; part[11] = m11;

#pragma unroll
    for (int off = 32; off > 0; off >>= 1) {
#pragma unroll
        for (int q = 0; q < NQ; ++q)
            part[q] += __shfl_down(part[q], off, 64);
    }
    // red/qout are overlaid in buf: ensure every wave's final buf reads are drained first
    __syncthreads();
    if (lam == 0) {
#pragma unroll
        for (int q = 0; q < NQ; ++q) redp[w * NQ + q] = part[q];
    }
    __syncthreads();
    if (tix < NQ) qoutp[tix] = redp[0 * NQ + tix] + redp[1 * NQ + tix] +
                               redp[2 * NQ + tix] + redp[3 * NQ + tix];
    __syncthreads();

    if (tix < NA) {
        float acc = fc_b[tix];
#pragma unroll
        for (int q = 0; q < NQ; ++q)
            acc += qoutp[q] * fc_w[tix * NQ + q];
        out[b * NA + tix] = acc;
    }
}

extern "C" void kernel_launch(void* const* d_in, const int* in_sizes, int n_in,
                              void* d_out, int out_size, void* d_ws, size_t ws_size,
                              hipStream_t stream) {
    const float* x   = (const float*)d_in[0];
    const float* wts = (const float*)d_in[1];
    const float* fcw = (const float*)d_in[2];
    const float* fcb = (const float*)d_in[3];
    float* tabs = (float*)d_ws;   // 272 f32 = 1088 B
    setup_kernel<<<1, 64, 0, stream>>>(wts, tabs);
    qdqn_kernel<<<BATCH, NT, 0, stream>>>(x, tabs, fcw, fcb, (float*)d_out);
}

// Round 2
// 148.149 us; speedup vs baseline: 1.0386x; 1.0386x over previous
//
#include <hip/hip_runtime.h>
#include <math.h>

#define NQ 12
#define NL 4
#define NA 6
#define BATCH 4096
#define NT 256
#define RSTR 17   // float (b32) row stride; odd -> conflict-free at 2-dword/bank b32 floor

typedef float f2 __attribute__((ext_vector_type(2)));

// HW-verified (R3-R10) packed complex primitives; (re,im) in a VGPR pair.
#define CMUL(d, u, a)  asm("v_pk_mul_f32 %0, %1, %2 op_sel_hi:[0,1]"                 : "=v"(d) : "v"(u), "v"(a))
#define CMACR(d, u, a) asm("v_pk_fma_f32 %0, %1, %2, %0 op_sel_hi:[0,1,1]"           : "+v"(d) : "v"(u), "v"(a))
#define CMACI(d, u, a) asm("v_pk_fma_f32 %0, %1, %2, %0 op_sel:[1,1,0] op_sel_hi:[1,0,1] neg_lo:[1,0,0]" : "+v"(d) : "v"(u), "v"(a))
// R10-verified scalar-broadcast variants (coefficient f2 = (c,s)):
#define RYMULS(d, u, a)  asm("v_pk_mul_f32 %0, %1, %2 op_sel:[1,0] op_sel_hi:[1,1]"  : "=v"(d) : "v"(u), "v"(a))
#define RYMACNS(d, u, a) asm("v_pk_fma_f32 %0, %1, %2, %0 op_sel:[1,0,0] op_sel_hi:[1,1,1] neg_lo:[1,0,0] neg_hi:[1,0,0]" : "+v"(d) : "v"(u), "v"(a))
#define WFENCE() asm volatile("s_waitcnt lgkmcnt(0)" ::: "memory")

// Real RY butterfly: n0 = c*a0 - s*a1 ; n1 = s*a0 + c*a1   (4 pk ops)
#define RYBFLY(A0, A1, CS) do { \
    f2 _a0 = (A0), _a1 = (A1), _n0, _n1; \
    CMUL  (_n0, CS, _a0); RYMACNS(_n0, CS, _a1); \
    RYMULS(_n1, CS, _a0); CMACR  (_n1, CS, _a1); \
    (A0) = _n0; (A1) = _n1; } while (0)

#define RYGATE(gidx, bq) do { \
    const f2 cs = *(const f2*)(rots + (gidx) * 2); \
    const int S = 1 << (bq); \
    _Pragma("unroll") \
    for (int m = 0; m < 8; ++m) { \
        const int j0 = ((m & ~(S - 1)) << 1) | (m & (S - 1)); \
        RYBFLY(st[j0], st[j0 + S], cs); \
    } } while (0)

// Circuit algebra (R10-verified): Rot = RZ(omega)*RY(theta)*RZ(phi); diagonals folded:
// RZ(phi_0) into init; D_l = RZ(omega_l)*CZ*RZ(phi_{l+1}) between RY layers; trailing
// RZ(omega_3)+CZ_3 dropped (probs phase-invariant).
// Layouts (R8-verified): L1: i=(lam5..lam0,w1,w0,j3..j0); L2: i=(lam5,lam4,j3..j0,w1,w0,lam3..0);
// L3: i=(j3,j2,lam5,lam4,w1,w0,j1,j0,lam3..0).
// T_a (L1<->L2, involution, wave-local) / T_b (L2<->L3, involution, cross-wave): R8 formulas.
// R12: transpose buffer split into b32 re/im passes over a float[256][17] buffer (17408 B).
//   Same pad-17 geometry -> all access patterns at the 2-dword/bank b32 floor (mod-32 verified
//   for writes tix*17+j, T_a (row_a+j)*17+col_a, T_b TBROW(j)*17+col_b; stride 17 is odd).
//   All LDS addresses are base + j*immediate -> no extra address VGPRs (R11 lesson: XOR swizzle
//   cost +20 VGPR, crossed the 64-VGPR occupancy granule, occupancy DROPPED).
//   Total LDS ~17.7 KB -> 8 blocks/CU (wave-capped), 32 waves/CU vs 16 at the f2 buffer.
//   T_a stays wave-local (fences only); T_b re/im passes need 3-4 barriers (im overwrites re).
// d_ws float layout: [0..95] 48 gates (c,s) | [96..143] alphas[4][12] | [144..271] dreg[4][16] (re,im)

__global__ void setup_kernel(const float* __restrict__ weights, float* __restrict__ ws) {
    const int t = threadIdx.x;   // 64 threads
    if (t < NL * NQ) {
        const float th = weights[t * 3 + 1];
        float s, c;
        sincosf(0.5f * th, &s, &c);
        ws[t * 2 + 0] = c; ws[t * 2 + 1] = s;
        const int r = t / NQ, q = t % NQ;
        float a;
        if (r == 0) a = 0.5f * weights[q * 3 + 0];
        else        a = 0.5f * (weights[((r - 1) * NQ + q) * 3 + 2] +
                                 weights[(r * NQ + q) * 3 + 0]);
        ws[96 + t] = a;
    }
    {
        const int d = t >> 4, j = t & 15;
        int wq[4];
        if (d == 1 || d == 3) { wq[0] = 0; wq[1] = 1; wq[2] = 6; wq[3] = 7; }
        else                  { wq[0] = 8; wq[1] = 9; wq[2] = 10; wq[3] = 11; }
        float g = 0.0f;
#pragma unroll
        for (int k = 0; k < 4; ++k) {
            const int q = wq[k];
            const float a = (d == 0) ? 0.5f * weights[q * 3 + 0]
                                     : 0.5f * (weights[((d - 1) * NQ + q) * 3 + 2] +
                                               weights[(d * NQ + q) * 3 + 0]);
            g += ((j >> (3 - k)) & 1) ? a : -a;
        }
        float sg, cg;
        sincosf(g, &sg, &cg);
        ws[144 + (d * 16 + j) * 2 + 0] = cg;
        ws[144 + (d * 16 + j) * 2 + 1] = sg;
    }
}

// st[j] *= (cos b, sin b) * dreg_tab[j]   (R10-verified)
__device__ __forceinline__ void apply_phase(f2* st, const float* tab, float beta) {
    float sb, cb;
    sincosf(beta, &sb, &cb);
    const f2 Dth = (f2){cb, sb};
#pragma unroll
    for (int j = 0; j < 16; ++j) {
        const f2 a = st[j];
        f2 t, u;
        CMUL(t, Dth, a); CMACI(t, Dth, a);
        const f2 dg = *(const f2*)(tab + 2 * j);
        CMUL(u, dg, t); CMACI(u, dg, t);
        st[j] = u;
    }
}

__global__ __launch_bounds__(NT) void qdqn_kernel(
    const float* __restrict__ x,       // [BATCH,12]
    const float* __restrict__ rots,    // d_ws tables
    const float* __restrict__ fc_w,    // [6,12]
    const float* __restrict__ fc_b,    // [6]
    float* __restrict__ out)           // [BATCH,6]
{
    __shared__ __align__(16) float bufr[NT * RSTR];   // 17408 B b32 transpose buffer
    __shared__ float encc[NQ], encs[NQ];
    __shared__ float red[4][NQ];
    __shared__ float qout[NQ];

    const int tix = threadIdx.x;
    const int lam = tix & 63;
    const int w   = tix >> 6;
    const int w1  = (w >> 1) & 1, w0 = w & 1;
    const int b   = blockIdx.x;

    const float* alph = rots + 96;
    const float* dreg = rots + 144;

    if (tix < NQ) {
        float s, c;
        sincosf(0.5f * x[b * NQ + tix], &s, &c);
        encc[tix] = c; encs[tix] = s;
    }
    __syncthreads();

    // --- RY product state in L1 (real) ---
    f2 st[16];
    {
        float pre = 1.0f;
#pragma unroll
        for (int q = 0; q < 6; ++q)
            pre *= ((lam >> (5 - q)) & 1) ? encs[q] : encc[q];
        pre *= w1 ? encs[6] : encc[6];
        pre *= w0 ? encs[7] : encc[7];
        const float c8 = encc[8],  s8 = encs[8];
        const float c9 = encc[9],  s9 = encs[9];
        const float cA = encc[10], sA = encs[10];
        const float cB = encc[11], sB = encs[11];
#pragma unroll
        for (int j = 0; j < 16; ++j) {
            float v = pre;
            v *= (j & 8) ? s8 : c8;
            v *= (j & 4) ? s9 : c9;
            v *= (j & 2) ? sA : cA;
            v *= (j & 1) ? sB : cB;
            st[j] = (f2){ v, 0.0f };
        }
    }

#define BETA_L1(al) ( (((lam >> 5) & 1) ? (al)[0] : -(al)[0]) + (((lam >> 4) & 1) ? (al)[1] : -(al)[1]) \
                    + (((lam >> 3) & 1) ? (al)[2] : -(al)[2]) + (((lam >> 2) & 1) ? (al)[3] : -(al)[3]) \
                    + (((lam >> 1) & 1) ? (al)[4] : -(al)[4]) + (((lam >> 0) & 1) ? (al)[5] : -(al)[5]) \
                    + (w1 ? (al)[6] : -(al)[6]) + (w0 ? (al)[7] : -(al)[7]) )
#define BETA_L3(al) ( (((lam >> 5) & 1) ? (al)[2] : -(al)[2]) + (((lam >> 4) & 1) ? (al)[3] : -(al)[3]) \
                    + (w1 ? (al)[4] : -(al)[4]) + (w0 ? (al)[5] : -(al)[5]) \
                    + (((lam >> 3) & 1) ? (al)[8] : -(al)[8]) + (((lam >> 2) & 1) ? (al)[9] : -(al)[9]) \
                    + (((lam >> 1) & 1) ? (al)[10] : -(al)[10]) + (((lam >> 0) & 1) ? (al)[11] : -(al)[11]) )

    // --- init diagonal: RZ(phi_0) in L1 ---
    apply_phase(st, dreg + 0 * 32, BETA_L1(alph + 0 * NQ));

    const int col_b = ((lam >> 4) << 2) | w;
    const int row_a = (w << 6) | (lam & 0x30);
    const int col_a = lam & 0xF;

#define TBROW(j) ((((j) & 3) << 6) | (((j) >> 2) << 4) | (lam & 15))

    // T_a (wave-local throughout: wave w only touches rows (w<<6)..(w<<6)+63): fences only.
#define TRANSPOSE_A_FWD() do { \
    WFENCE(); \
    _Pragma("unroll") for (int j = 0; j < 16; ++j) bufr[tix * RSTR + j] = st[j].x; \
    WFENCE(); \
    _Pragma("unroll") for (int j = 0; j < 16; ++j) st[j].x = bufr[(row_a + j) * RSTR + col_a]; \
    WFENCE(); \
    _Pragma("unroll") for (int j = 0; j < 16; ++j) bufr[tix * RSTR + j] = st[j].y; \
    WFENCE(); \
    _Pragma("unroll") for (int j = 0; j < 16; ++j) st[j].y = bufr[(row_a + j) * RSTR + col_a]; \
    } while (0)

#pragma unroll 1
    for (int h = 0; h < 2; ++h) {
        // ============ forward layer l = 2h : L1 -> L2 -> L3 ============
        {
            const int gb = (2 * h) * NQ;
            RYGATE(gb + 11, 0); RYGATE(gb + 10, 1); RYGATE(gb + 9, 2); RYGATE(gb + 8, 3);
            TRANSPOSE_A_FWD();                      // wave-local (prior readers in-wave or none)
            RYGATE(gb + 5, 0); RYGATE(gb + 4, 1); RYGATE(gb + 3, 2); RYGATE(gb + 2, 3);
            // T_b (cross-wave reads), re pass then im pass
            WFENCE();
#pragma unroll
            for (int j = 0; j < 16; ++j) bufr[tix * RSTR + j] = st[j].x;
            __syncthreads();
#pragma unroll
            for (int j = 0; j < 16; ++j) st[j].x = bufr[TBROW(j) * RSTR + col_b];
            __syncthreads();   // drain re reads before im overwrites
#pragma unroll
            for (int j = 0; j < 16; ++j) bufr[tix * RSTR + j] = st[j].y;
            __syncthreads();
#pragma unroll
            for (int j = 0; j < 16; ++j) st[j].y = bufr[TBROW(j) * RSTR + col_b];
            RYGATE(gb + 7, 0); RYGATE(gb + 6, 1); RYGATE(gb + 1, 2); RYGATE(gb + 0, 3);
            // CZ sign in L3 (R8-verified)
            {
                const int l5 = (lam >> 5) & 1, l4 = (lam >> 4) & 1, l3 = (lam >> 3) & 1;
                const int par = (l5 & l4) + (l4 & w1) + (w1 & w0) + __popc(lam & (lam >> 1) & 0x7);
                const float base = (par & 1) ? -1.0f : 1.0f;
                const float fA = l5 ? -1.0f : 1.0f;
                const float fB = w0 ? -1.0f : 1.0f;
                const float fC = l3 ? -1.0f : 1.0f;
#pragma unroll
                for (int j = 0; j < 16; ++j) {
                    float s = base;
                    if (j & 4) s *= fA;
                    if (j & 2) s *= fB;
                    if (j & 1) s *= fC;
                    if ((((j & 12) == 12) ? 1 : 0) ^ (((j & 3) == 3) ? 1 : 0)) s = -s;
                    st[j] *= s;
                }
            }
            // fused RZ diagonal, row 2h+1, in L3
            apply_phase(st, dreg + (2 * h + 1) * 32, BETA_L3(alph + (2 * h + 1) * NQ));
        }
        // ============ reverse layer l = 2h+1 : L3 -> L2 -> L1 ============
        {
            const int gb = (2 * h + 1) * NQ;
            RYGATE(gb + 7, 0); RYGATE(gb + 6, 1); RYGATE(gb + 1, 2); RYGATE(gb + 0, 3);
            // T_b back (involution; prior T_b reads cross-wave -> barrier before writes)
            __syncthreads();
#pragma unroll
            for (int j = 0; j < 16; ++j) bufr[tix * RSTR + j] = st[j].x;
            __syncthreads();
#pragma unroll
            for (int j = 0; j < 16; ++j) st[j].x = bufr[TBROW(j) * RSTR + col_b];
            __syncthreads();   // drain re reads before im overwrites
#pragma unroll
            for (int j = 0; j < 16; ++j) bufr[tix * RSTR + j] = st[j].y;
            __syncthreads();
#pragma unroll
            for (int j = 0; j < 16; ++j) st[j].y = bufr[TBROW(j) * RSTR + col_b];
            RYGATE(gb + 5, 0); RYGATE(gb + 4, 1); RYGATE(gb + 3, 2); RYGATE(gb + 2, 3);
            // T_a back (prior T_b reads cross-wave -> barrier before writes; then wave-local)
            __syncthreads();
#pragma unroll
            for (int j = 0; j < 16; ++j) bufr[tix * RSTR + j] = st[j].x;
            WFENCE();
#pragma unroll
            for (int j = 0; j < 16; ++j) st[j].x = bufr[(row_a + j) * RSTR + col_a];
            WFENCE();
#pragma unroll
            for (int j = 0; j < 16; ++j) bufr[tix * RSTR + j] = st[j].y;
            WFENCE();
#pragma unroll
            for (int j = 0; j < 16; ++j) st[j].y = bufr[(row_a + j) * RSTR + col_a];
            RYGATE(gb + 11, 0); RYGATE(gb + 10, 1); RYGATE(gb + 9, 2); RYGATE(gb + 8, 3);
            if (h == 0) {
                // CZ sign in L1 (R6/R8-verified)
                {
                    const int par = __popc(lam & (lam >> 1)) + ((lam & 1) & w1) + (w1 & w0);
                    const float base = (par & 1) ? -1.0f : 1.0f;
                    const float sHi = w0 ? -base : base;
#pragma unroll
                    for (int j = 0; j < 16; ++j) {
                        float s = (j & 8) ? sHi : base;
                        if (__popc(j & (j >> 1)) & 1) s = -s;
                        st[j] *= s;
                    }
                }
                // fused RZ diagonal, row 2, in L1
                apply_phase(st, dreg + 2 * 32, BETA_L1(alph + 2 * NQ));
            }
            // h==1: trailing diagonals dropped (probs phase-invariant)
        }
    }

    // --- measurement in L1 ---
    float tot = 0.f, m8 = 0.f, m9 = 0.f, m10 = 0.f, m11 = 0.f;
#pragma unroll
    for (int j = 0; j < 16; ++j) {
        const float p = st[j].x * st[j].x + st[j].y * st[j].y;
        tot += p;
        m8  += (j & 8) ? -p : p;
        m9  += (j & 4) ? -p : p;
        m10 += (j & 2) ? -p : p;
        m11 += (j & 1) ? -p : p;
    }
    float part[NQ];
#pragma unroll
    for (int q = 0; q < 6; ++q)
        part[q] = ((lam >> (5 - q)) & 1) ? -tot : tot;
    part[6] = w1 ? -tot : tot;
    part[7] = w0 ? -tot : tot;
    part[8] = m8; part[9] = m9; part[10] = m10; part[11] = m11;

#pragma unroll
    for (int off = 32; off > 0; off >>= 1) {
#pragma unroll
        for (int q = 0; q < NQ; ++q)
            part[q] += __shfl_down(part[q], off, 64);
    }
    if (lam == 0) {
#pragma unroll
        for (int q = 0; q < NQ; ++q) red[w][q] = part[q];
    }
    __syncthreads();
    if (tix < NQ) qout[tix] = red[0][tix] + red[1][tix] + red[2][tix] + red[3][tix];
    __syncthreads();

    if (tix < NA) {
        float acc = fc_b[tix];
#pragma unroll
        for (int q = 0; q < NQ; ++q)
            acc += qout[q] * fc_w[tix * NQ + q];
        out[b * NA + tix] = acc;
    }
}

extern "C" void kernel_launch(void* const* d_in, const int* in_sizes, int n_in,
                              void* d_out, int out_size, void* d_ws, size_t ws_size,
                              hipStream_t stream) {
    const float* x   = (const float*)d_in[0];
    const float* wts = (const float*)d_in[1];
    const float* fcw = (const float*)d_in[2];
    const float* fcb = (const float*)d_in[3];
    float* tabs = (float*)d_ws;   // 272 f32 = 1088 B
    setup_kernel<<<1, 64, 0, stream>>>(wts, tabs);
    qdqn_kernel<<<BATCH, NT, 0, stream>>>(x, tabs, fcw, fcb, (float*)d_out);
}